// Round 2
// baseline (142.375 us; speedup 1.0000x reference)
//
#include <hip/hip_runtime.h>
#include <hip/hip_bf16.h>

constexpr int HIDDEN  = 256;   // per-bag hidden dim
constexpr int BAG     = 32;
constexpr int CHUNK_R = 64;    // batch rows per gather block
constexpr int NSLICE  = 16;    // column slices of 16 floats (64 B = 1 line)
constexpr int SLICE_F = 16;

// ---------------- kernel 1: XCD-sliced bag-sum gather ----------------
// block = one (slice, 64-row chunk). slice -> XCD via blockIdx%8 so each
// XCD's L2 only sees ~2 slices (2x2.6 MB) of the 42 MB table.
__global__ __launch_bounds__(256) void k1_gather(
    const int*   __restrict__ us,
    const int*   __restrict__ them,
    const float* __restrict__ emb,
    float*       __restrict__ x,      // [batch][2*HIDDEN]
    int nchunks)                       // batch / CHUNK_R
{
    __shared__ int idx_lds[CHUNK_R][2 * BAG + 1];   // +1 pad: conflict-free

    const int b        = blockIdx.x;
    const int per_phase = 8 * nchunks;
    const int phase    = b / per_phase;        // 0..1
    const int rem      = b % per_phase;
    const int xcd      = rem & 7;
    const int chunk    = rem >> 3;
    const int slice    = xcd + (phase << 3);   // 0..15
    const int tid      = threadIdx.x;

    // stage this chunk's 64x(32+32) indices, coalesced
    const int base_i = chunk * (CHUNK_R * BAG);
#pragma unroll
    for (int k = 0; k < (CHUNK_R * BAG) / 256; ++k) {   // 8 iters
        const int t = k * 256 + tid;
        const int r = t >> 5, c = t & 31;
        idx_lds[r][c]       = us[base_i + t];
        idx_lds[r][BAG + c] = them[base_i + t];
    }
    __syncthreads();

    const int r = tid >> 2;          // row within chunk (0..63)
    const int q = tid & 3;           // float4 quarter of the slice
    const float4* emb4 = reinterpret_cast<const float4*>(emb);
    const int col4 = slice * (SLICE_F / 4) + q;   // float4 col within row

    float4 aU = make_float4(0.f, 0.f, 0.f, 0.f);
    float4 aT = make_float4(0.f, 0.f, 0.f, 0.f);
#pragma unroll
    for (int i = 0; i < BAG; ++i) {
        const int iu = idx_lds[r][i];
        const int it = idx_lds[r][BAG + i];
        const float4 vu = emb4[(size_t)iu * (HIDDEN / 4) + col4];
        const float4 vt = emb4[(size_t)it * (HIDDEN / 4) + col4];
        aU.x += vu.x; aU.y += vu.y; aU.z += vu.z; aU.w += vu.w;
        aT.x += vt.x; aT.y += vt.y; aT.z += vt.z; aT.w += vt.w;
    }

    const int row = chunk * CHUNK_R + r;
    float4* x4 = reinterpret_cast<float4*>(x);
    x4[(size_t)row * (2 * HIDDEN / 4) + col4]                  = aU;  // us part
    x4[(size_t)row * (2 * HIDDEN / 4) + (HIDDEN / 4) + col4]   = aT;  // them part
}

// ---------------- kernel 2: tiny MLP (proven mapping from R0) ----------------
__global__ __launch_bounds__(256) void k2_mlp(
    const float* __restrict__ x,
    const float* __restrict__ w1, const float* __restrict__ b1,
    const float* __restrict__ w2, const float* __restrict__ b2,
    const float* __restrict__ w3, const float* __restrict__ b3,
    float*       __restrict__ out)
{
    __shared__ float x_lds[4][2 * HIDDEN];
    __shared__ float y1_lds[4][32];
    __shared__ float y2_lds[4][32];

    const int tid  = threadIdx.x;
    const int wave = tid >> 6;
    const int lane = tid & 63;
    const int row  = blockIdx.x * 4 + wave;

    {   // stage this wave's x row, coalesced float4
        const float4* xr = reinterpret_cast<const float4*>(x + (size_t)row * (2 * HIDDEN));
        float4* xl = reinterpret_cast<float4*>(&x_lds[wave][0]);
        xl[lane]      = xr[lane];
        xl[64 + lane] = xr[64 + lane];
    }
    __syncthreads();

    // fc1: 512 -> 32, clip(0,1); 2 threads per (row, j)
    {
        const int r    = tid >> 6;
        const int sub  = tid & 63;
        const int j    = sub >> 1;
        const int half = sub & 1;
        const float4* xr = reinterpret_cast<const float4*>(&x_lds[r][0]) + half * 64;
        const float4* wr = reinterpret_cast<const float4*>(w1 + (size_t)j * (2 * HIDDEN)) + half * 64;
        float s = 0.f;
#pragma unroll 8
        for (int k = 0; k < 64; ++k) {
            const float4 xk = xr[k];
            const float4 wk = wr[k];
            s += xk.x * wk.x + xk.y * wk.y + xk.z * wk.z + xk.w * wk.w;
        }
        s += __shfl_xor(s, 1);
        if (half == 0) {
            s += b1[j];
            y1_lds[r][j] = fminf(fmaxf(s, 0.f), 1.f);
        }
    }
    __syncthreads();

    // fc2: 32 -> 32, clip(0,1)
    if (tid < 4 * 32) {
        const int r = tid >> 5;
        const int j = tid & 31;
        const float* wr = w2 + j * 32;
        float s = b2[j];
#pragma unroll
        for (int k = 0; k < 32; ++k) s += y1_lds[r][k] * wr[k];
        y2_lds[r][j] = fminf(fmaxf(s, 0.f), 1.f);
    }
    __syncthreads();

    // fc3: 32 -> 1, tanh
    if (tid < 4) {
        const int r = tid;
        float s = b3[0];
#pragma unroll
        for (int k = 0; k < 32; ++k) s += y2_lds[r][k] * w3[k];
        out[blockIdx.x * 4 + r] = tanhf(s);
    }
}

// ---------------- fallback: R0 monolithic kernel (if ws too small) ----------
__global__ __launch_bounds__(256) void nnue_fused(
    const int*   __restrict__ us,
    const int*   __restrict__ them,
    const float* __restrict__ emb,
    const float* __restrict__ w1, const float* __restrict__ b1,
    const float* __restrict__ w2, const float* __restrict__ b2,
    const float* __restrict__ w3, const float* __restrict__ b3,
    float*       __restrict__ out)
{
    __shared__ float x_lds[4][2 * HIDDEN];
    __shared__ float y1_lds[4][32];
    __shared__ float y2_lds[4][32];

    const int tid  = threadIdx.x;
    const int wave = tid >> 6;
    const int lane = tid & 63;
    const int row  = blockIdx.x * 4 + wave;

    int myidx;
    {
        const int* up = us   + (size_t)row * BAG;
        const int* tp = them + (size_t)row * BAG;
        myidx = (lane < BAG) ? up[lane] : tp[lane - BAG];
    }
    const float4* emb4 = reinterpret_cast<const float4*>(emb);
    float4 accU = make_float4(0.f, 0.f, 0.f, 0.f);
    float4 accT = make_float4(0.f, 0.f, 0.f, 0.f);
#pragma unroll
    for (int i = 0; i < BAG; ++i) {
        const int iu = __shfl(myidx, i);
        const int it = __shfl(myidx, BAG + i);
        const float4 vu = emb4[(size_t)iu * (HIDDEN / 4) + lane];
        const float4 vt = emb4[(size_t)it * (HIDDEN / 4) + lane];
        accU.x += vu.x; accU.y += vu.y; accU.z += vu.z; accU.w += vu.w;
        accT.x += vt.x; accT.y += vt.y; accT.z += vt.z; accT.w += vt.w;
    }
    {
        float4* xv = reinterpret_cast<float4*>(&x_lds[wave][0]);
        xv[lane]      = accU;
        xv[64 + lane] = accT;
    }
    __syncthreads();
    {
        const int r    = tid >> 6;
        const int sub  = tid & 63;
        const int j    = sub >> 1;
        const int half = sub & 1;
        const float4* xr = reinterpret_cast<const float4*>(&x_lds[r][0]) + half * 64;
        const float4* wr = reinterpret_cast<const float4*>(w1 + (size_t)j * (2 * HIDDEN)) + half * 64;
        float s = 0.f;
#pragma unroll 8
        for (int k = 0; k < 64; ++k) {
            const float4 xk = xr[k];
            const float4 wk = wr[k];
            s += xk.x * wk.x + xk.y * wk.y + xk.z * wk.z + xk.w * wk.w;
        }
        s += __shfl_xor(s, 1);
        if (half == 0) { s += b1[j]; y1_lds[r][j] = fminf(fmaxf(s, 0.f), 1.f); }
    }
    __syncthreads();
    if (tid < 4 * 32) {
        const int r = tid >> 5;
        const int j = tid & 31;
        const float* wr = w2 + j * 32;
        float s = b2[j];
#pragma unroll
        for (int k = 0; k < 32; ++k) s += y1_lds[r][k] * wr[k];
        y2_lds[r][j] = fminf(fmaxf(s, 0.f), 1.f);
    }
    __syncthreads();
    if (tid < 4) {
        const int r = tid;
        float s = b3[0];
#pragma unroll
        for (int k = 0; k < 32; ++k) s += y2_lds[r][k] * w3[k];
        out[blockIdx.x * 4 + r] = tanhf(s);
    }
}

extern "C" void kernel_launch(void* const* d_in, const int* in_sizes, int n_in,
                              void* d_out, int out_size, void* d_ws, size_t ws_size,
                              hipStream_t stream) {
    const int*   us   = (const int*)  d_in[0];
    const int*   them = (const int*)  d_in[1];
    const float* emb  = (const float*)d_in[2];
    const float* w1   = (const float*)d_in[3];
    const float* b1   = (const float*)d_in[4];
    const float* w2   = (const float*)d_in[5];
    const float* b2   = (const float*)d_in[6];
    const float* w3   = (const float*)d_in[7];
    const float* b3   = (const float*)d_in[8];
    float* out = (float*)d_out;

    const int batch = in_sizes[0] / BAG;              // 8192
    const size_t x_bytes = (size_t)batch * 2 * HIDDEN * sizeof(float);

    if (ws_size >= x_bytes && batch % CHUNK_R == 0) {
        float* x = (float*)d_ws;
        const int nchunks = batch / CHUNK_R;          // 128
        const int grid1   = NSLICE * nchunks;         // 2048
        k1_gather<<<grid1, 256, 0, stream>>>(us, them, emb, x, nchunks);
        k2_mlp<<<batch / 4, 256, 0, stream>>>(x, w1, b1, w2, b2, w3, b3, out);
    } else {
        nnue_fused<<<(batch + 3) / 4, 256, 0, stream>>>(us, them, emb,
                                                        w1, b1, w2, b2, w3, b3, out);
    }
}

// Round 3
// 69.462 us; speedup vs baseline: 2.0497x; 2.0497x over previous
//
#include <hip/hip_runtime.h>
#include <hip/hip_bf16.h>

constexpr int HIDDEN = 256;
constexpr int BAG    = 32;
constexpr int FEAT   = 41025;   // FEATURE_COUNT + 1 (includes zero pad row)
constexpr int NJ     = 64;      // P columns: [0:32]=us-proj, [32:64]=them-proj

// ---------- k0: P[f][j] = dot(emb[f], W2d[j]),  W2d[j] = fc1_w[j&31][(j>>5)*256 : +256]
// block: 64 rows x 64 cols, 256 threads, 4x4 register blocking.
// W chunk [64 j][64 k] staged in LDS with XOR swizzle; emb broadcast from global.
__global__ __launch_bounds__(256) void k0_project(
    const float* __restrict__ emb,
    const float* __restrict__ fc1_w,
    float*       __restrict__ P)
{
    __shared__ float4 w_lds[64 * 16];   // float4 idx = j*16 + (kq ^ (j&15))

    const int tid = threadIdx.x;
    const int rg  = tid >> 4;           // 0..15 -> rows rg*4 .. rg*4+3
    const int jg  = tid & 15;           // 0..15 -> cols jg*4 .. jg*4+3
    const int f0  = blockIdx.x * 64;

    int fr[4];
#pragma unroll
    for (int i = 0; i < 4; ++i) {
        const int f = f0 + rg * 4 + i;
        fr[i] = (f < FEAT) ? f : (FEAT - 1);   // clamp; extra rows not stored
    }
    float acc[4][4];
#pragma unroll
    for (int i = 0; i < 4; ++i)
#pragma unroll
        for (int ii = 0; ii < 4; ++ii) acc[i][ii] = 0.f;

    const float4* emb4 = reinterpret_cast<const float4*>(emb);

    for (int kc = 0; kc < 4; ++kc) {    // k-chunks of 64
        if (kc) __syncthreads();
        // stage W chunk: 1024 float4s, coalesced, XOR-swizzled into LDS
#pragma unroll
        for (int m = 0; m < 4; ++m) {
            const int idx = m * 256 + tid;
            const int j = idx >> 4, kq = idx & 15;
            const float* wsrc = fc1_w + (size_t)(j & 31) * 512 + (j >> 5) * 256
                                      + kc * 64 + kq * 4;
            w_lds[j * 16 + (kq ^ (j & 15))] = *reinterpret_cast<const float4*>(wsrc);
        }
        __syncthreads();

#pragma unroll
        for (int kq = 0; kq < 16; ++kq) {
            float4 e4[4], w4[4];
#pragma unroll
            for (int i = 0; i < 4; ++i)
                e4[i] = emb4[(size_t)fr[i] * 64 + kc * 16 + kq];   // broadcast across jg
#pragma unroll
            for (int ii = 0; ii < 4; ++ii) {
                const int j = jg * 4 + ii;
                w4[ii] = w_lds[j * 16 + (kq ^ (j & 15))];          // ~2-way, conflict-free
            }
#pragma unroll
            for (int i = 0; i < 4; ++i)
#pragma unroll
                for (int ii = 0; ii < 4; ++ii)
                    acc[i][ii] += e4[i].x * w4[ii].x + e4[i].y * w4[ii].y
                                + e4[i].z * w4[ii].z + e4[i].w * w4[ii].w;
        }
    }

    float4* P4 = reinterpret_cast<float4*>(P);
#pragma unroll
    for (int i = 0; i < 4; ++i) {
        const int f = f0 + rg * 4 + i;
        if (f < FEAT)
            P4[(size_t)f * 16 + jg] = make_float4(acc[i][0], acc[i][1],
                                                  acc[i][2], acc[i][3]);
    }
}

// ---------- k1: gather P rows (128 B each) + fused MLP. One wave per batch row.
__global__ __launch_bounds__(256) void k1_gather_mlp(
    const int*   __restrict__ us,
    const int*   __restrict__ them,
    const float* __restrict__ P,
    const float* __restrict__ b1,
    const float* __restrict__ w2, const float* __restrict__ b2,
    const float* __restrict__ w3, const float* __restrict__ b3,
    float*       __restrict__ out)
{
    __shared__ float w2_lds[32][33];
    __shared__ float y1_lds[4][32];

    const int tid  = threadIdx.x;
    const int wave = tid >> 6;
    const int lane = tid & 63;

    for (int k = tid; k < 32 * 32; k += 256)
        w2_lds[k >> 5][k & 31] = w2[k];
    __syncthreads();

    const int row = blockIdx.x * 4 + wave;
    int idx;
    {
        const int* up = us   + (size_t)row * BAG;
        const int* tp = them + (size_t)row * BAG;
        idx = (lane < BAG) ? up[lane] : tp[lane - BAG];
    }

    // lane j<32 accumulates us-part col j; lane 32+j accumulates them-part col 32+j
    float acc = 0.f;
    const int srcbase = lane & 32;
#pragma unroll
    for (int i = 0; i < BAG; ++i) {
        const int f = __shfl(idx, srcbase + i);
        acc += P[(size_t)f * NJ + lane];
    }
    acc += __shfl_xor(acc, 32);            // lane j<32: full fc1_out[j] - b1[j]

    if (lane < 32)
        y1_lds[wave][lane] = fminf(fmaxf(acc + b1[lane], 0.f), 1.f);
    __syncthreads();

    float r3 = 0.f;
    if (lane < 32) {
        float s = b2[lane];
#pragma unroll
        for (int k = 0; k < 32; ++k) s += y1_lds[wave][k] * w2_lds[lane][k];
        r3 = fminf(fmaxf(s, 0.f), 1.f) * w3[lane];
    }
    r3 += __shfl_xor(r3, 16); r3 += __shfl_xor(r3, 8); r3 += __shfl_xor(r3, 4);
    r3 += __shfl_xor(r3, 2);  r3 += __shfl_xor(r3, 1);
    if (lane == 0) out[row] = tanhf(r3 + b3[0]);
}

// ---------- fallback: R0 monolithic kernel (if ws too small) ----------
__global__ __launch_bounds__(256) void nnue_fused(
    const int*   __restrict__ us,
    const int*   __restrict__ them,
    const float* __restrict__ emb,
    const float* __restrict__ w1, const float* __restrict__ b1,
    const float* __restrict__ w2, const float* __restrict__ b2,
    const float* __restrict__ w3, const float* __restrict__ b3,
    float*       __restrict__ out)
{
    __shared__ float x_lds[4][2 * HIDDEN];
    __shared__ float y1_lds[4][32];
    __shared__ float y2_lds[4][32];

    const int tid  = threadIdx.x;
    const int wave = tid >> 6;
    const int lane = tid & 63;
    const int row  = blockIdx.x * 4 + wave;

    int myidx;
    {
        const int* up = us   + (size_t)row * BAG;
        const int* tp = them + (size_t)row * BAG;
        myidx = (lane < BAG) ? up[lane] : tp[lane - BAG];
    }
    const float4* emb4 = reinterpret_cast<const float4*>(emb);
    float4 accU = make_float4(0.f, 0.f, 0.f, 0.f);
    float4 accT = make_float4(0.f, 0.f, 0.f, 0.f);
#pragma unroll
    for (int i = 0; i < BAG; ++i) {
        const int iu = __shfl(myidx, i);
        const int it = __shfl(myidx, BAG + i);
        const float4 vu = emb4[(size_t)iu * (HIDDEN / 4) + lane];
        const float4 vt = emb4[(size_t)it * (HIDDEN / 4) + lane];
        accU.x += vu.x; accU.y += vu.y; accU.z += vu.z; accU.w += vu.w;
        accT.x += vt.x; accT.y += vt.y; accT.z += vt.z; accT.w += vt.w;
    }
    {
        float4* xv = reinterpret_cast<float4*>(&x_lds[wave][0]);
        xv[lane]      = accU;
        xv[64 + lane] = accT;
    }
    __syncthreads();
    {
        const int r    = tid >> 6;
        const int sub  = tid & 63;
        const int j    = sub >> 1;
        const int half = sub & 1;
        const float4* xr = reinterpret_cast<const float4*>(&x_lds[r][0]) + half * 64;
        const float4* wr = reinterpret_cast<const float4*>(w1 + (size_t)j * (2 * HIDDEN)) + half * 64;
        float s = 0.f;
#pragma unroll 8
        for (int k = 0; k < 64; ++k) {
            const float4 xk = xr[k];
            const float4 wk = wr[k];
            s += xk.x * wk.x + xk.y * wk.y + xk.z * wk.z + xk.w * wk.w;
        }
        s += __shfl_xor(s, 1);
        if (half == 0) { s += b1[j]; y1_lds[r][j] = fminf(fmaxf(s, 0.f), 1.f); }
    }
    __syncthreads();
    if (tid < 4 * 32) {
        const int r = tid >> 5;
        const int j = tid & 31;
        const float* wr = w2 + j * 32;
        float s = b2[j];
#pragma unroll
        for (int k = 0; k < 32; ++k) s += y1_lds[r][k] * wr[k];
        y2_lds[r][j] = fminf(fmaxf(s, 0.f), 1.f);
    }
    __syncthreads();
    if (tid < 4) {
        const int r = tid;
        float s = b3[0];
#pragma unroll
        for (int k = 0; k < 32; ++k) s += y2_lds[r][k] * w3[k];
        out[blockIdx.x * 4 + r] = tanhf(s);
    }
}

extern "C" void kernel_launch(void* const* d_in, const int* in_sizes, int n_in,
                              void* d_out, int out_size, void* d_ws, size_t ws_size,
                              hipStream_t stream) {
    const int*   us   = (const int*)  d_in[0];
    const int*   them = (const int*)  d_in[1];
    const float* emb  = (const float*)d_in[2];
    const float* w1   = (const float*)d_in[3];
    const float* b1   = (const float*)d_in[4];
    const float* w2   = (const float*)d_in[5];
    const float* b2   = (const float*)d_in[6];
    const float* w3   = (const float*)d_in[7];
    const float* b3   = (const float*)d_in[8];
    float* out = (float*)d_out;

    const int batch = in_sizes[0] / BAG;                    // 8192
    const size_t p_bytes = (size_t)FEAT * NJ * sizeof(float);  // 10.5 MB

    if (ws_size >= p_bytes) {
        float* P = (float*)d_ws;
        const int grid0 = (FEAT + 63) / 64;                 // 642
        k0_project<<<grid0, 256, 0, stream>>>(emb, w1, P);
        k1_gather_mlp<<<batch / 4, 256, 0, stream>>>(us, them, P,
                                                     b1, w2, b2, w3, b3, out);
    } else {
        nnue_fused<<<(batch + 3) / 4, 256, 0, stream>>>(us, them, emb,
                                                        w1, b1, w2, b2, w3, b3, out);
    }
}

// Round 4
// 48.730 us; speedup vs baseline: 2.9217x; 1.4254x over previous
//
#include <hip/hip_runtime.h>
#include <hip/hip_bf16.h>

constexpr int HIDDEN = 256;
constexpr int BAG    = 32;
constexpr int FEAT   = 41025;   // FEATURE_COUNT + 1 (includes zero pad row)
constexpr int NJ     = 64;      // P columns: [0:32]=us-proj, [32:64]=them-proj

// ---------- k0: P[f][j] = dot(emb[f], W2d[j]),  W2d[j] = fc1_w[j&31][(j>>5)*256 : +256]
// block: 64 rows x 64 cols, 256 threads, thread = 4 rows x 4 cols.
// Thread (rg=tid>>4, jg=tid&15): rows f0+rg*4+i, cols j = jg + 16*ii  (j stride 1
// across lanes -> conflict-free LDS with +1 float4 pad).
__global__ __launch_bounds__(256, 3) void k0_project(
    const float* __restrict__ emb,
    const float* __restrict__ fc1_w,
    float*       __restrict__ P)
{
    __shared__ float4 w_lds[64][17];    // [j][kq] one 64-float k-chunk, padded

    const int tid = threadIdx.x;
    const int rg  = tid >> 4;           // 0..15
    const int jg  = tid & 15;           // 0..15
    const int f0  = blockIdx.x * 64;

    long fr[4];
#pragma unroll
    for (int i = 0; i < 4; ++i) {
        const int f = f0 + rg * 4 + i;
        fr[i] = (f < FEAT) ? f : (FEAT - 1);   // clamp; extra rows not stored
    }
    float acc[4][4];
#pragma unroll
    for (int i = 0; i < 4; ++i)
#pragma unroll
        for (int ii = 0; ii < 4; ++ii) acc[i][ii] = 0.f;

    const float4* emb4 = reinterpret_cast<const float4*>(emb);

    for (int kc = 0; kc < 4; ++kc) {    // k-chunks of 64 floats
        if (kc) __syncthreads();
        // stage W chunk: 1024 float4s, coalesced; (j*17+kq)%8 spreads banks
#pragma unroll
        for (int m = 0; m < 4; ++m) {
            const int idx = m * 256 + tid;
            const int j = idx >> 4, kq = idx & 15;
            const float* wsrc = fc1_w + (size_t)(j & 31) * 512 + (j >> 5) * 256
                                      + kc * 64 + kq * 4;
            w_lds[j][kq] = *reinterpret_cast<const float4*>(wsrc);
        }
        __syncthreads();

#pragma unroll 4
        for (int kq = 0; kq < 16; ++kq) {
            float4 e4[4], w4[4];
#pragma unroll
            for (int i = 0; i < 4; ++i)
                e4[i] = emb4[fr[i] * 64 + kc * 16 + kq];   // 4 distinct addrs/wave
#pragma unroll
            for (int ii = 0; ii < 4; ++ii)
                w4[ii] = w_lds[jg + 16 * ii][kq];          // 2-way max -> free
#pragma unroll
            for (int i = 0; i < 4; ++i)
#pragma unroll
                for (int ii = 0; ii < 4; ++ii)
                    acc[i][ii] += e4[i].x * w4[ii].x + e4[i].y * w4[ii].y
                                + e4[i].z * w4[ii].z + e4[i].w * w4[ii].w;
        }
    }

#pragma unroll
    for (int i = 0; i < 4; ++i) {
        const int f = f0 + rg * 4 + i;
        if (f < FEAT) {
#pragma unroll
            for (int ii = 0; ii < 4; ++ii)
                P[(size_t)f * NJ + jg + 16 * ii] = acc[i][ii];  // 4x 64B segments
        }
    }
}

// ---------- k1: gather P rows (128 B each) + fused MLP. One wave per batch row.
__global__ __launch_bounds__(256) void k1_gather_mlp(
    const int*   __restrict__ us,
    const int*   __restrict__ them,
    const float* __restrict__ P,
    const float* __restrict__ b1,
    const float* __restrict__ w2, const float* __restrict__ b2,
    const float* __restrict__ w3, const float* __restrict__ b3,
    float*       __restrict__ out)
{
    __shared__ float w2_lds[32][33];
    __shared__ float y1_lds[4][32];

    const int tid  = threadIdx.x;
    const int wave = tid >> 6;
    const int lane = tid & 63;

    for (int k = tid; k < 32 * 32; k += 256)
        w2_lds[k >> 5][k & 31] = w2[k];
    __syncthreads();

    const int row = blockIdx.x * 4 + wave;
    int idx;
    {
        const int* up = us   + (size_t)row * BAG;
        const int* tp = them + (size_t)row * BAG;
        idx = (lane < BAG) ? up[lane] : tp[lane - BAG];
    }

    // lane j<32 accumulates us-part col j; lane 32+j accumulates them-part col 32+j
    float acc = 0.f;
    const int srcbase = lane & 32;
#pragma unroll
    for (int i = 0; i < BAG; ++i) {
        const int f = __shfl(idx, srcbase + i);
        acc += P[(size_t)f * NJ + lane];
    }
    acc += __shfl_xor(acc, 32);            // lane j<32: full fc1_out[j] - b1[j]

    if (lane < 32)
        y1_lds[wave][lane] = fminf(fmaxf(acc + b1[lane], 0.f), 1.f);
    __syncthreads();

    float r3 = 0.f;
    if (lane < 32) {
        float s = b2[lane];
#pragma unroll
        for (int k = 0; k < 32; ++k) s += y1_lds[wave][k] * w2_lds[lane][k];
        r3 = fminf(fmaxf(s, 0.f), 1.f) * w3[lane];
    }
    r3 += __shfl_xor(r3, 16); r3 += __shfl_xor(r3, 8); r3 += __shfl_xor(r3, 4);
    r3 += __shfl_xor(r3, 2);  r3 += __shfl_xor(r3, 1);
    if (lane == 0) out[row] = tanhf(r3 + b3[0]);
}

// ---------- fallback: R0 monolithic kernel (if ws too small) ----------
__global__ __launch_bounds__(256) void nnue_fused(
    const int*   __restrict__ us,
    const int*   __restrict__ them,
    const float* __restrict__ emb,
    const float* __restrict__ w1, const float* __restrict__ b1,
    const float* __restrict__ w2, const float* __restrict__ b2,
    const float* __restrict__ w3, const float* __restrict__ b3,
    float*       __restrict__ out)
{
    __shared__ float x_lds[4][2 * HIDDEN];
    __shared__ float y1_lds[4][32];
    __shared__ float y2_lds[4][32];

    const int tid  = threadIdx.x;
    const int wave = tid >> 6;
    const int lane = tid & 63;
    const int row  = blockIdx.x * 4 + wave;

    int myidx;
    {
        const int* up = us   + (size_t)row * BAG;
        const int* tp = them + (size_t)row * BAG;
        myidx = (lane < BAG) ? up[lane] : tp[lane - BAG];
    }
    const float4* emb4 = reinterpret_cast<const float4*>(emb);
    float4 accU = make_float4(0.f, 0.f, 0.f, 0.f);
    float4 accT = make_float4(0.f, 0.f, 0.f, 0.f);
#pragma unroll
    for (int i = 0; i < BAG; ++i) {
        const int iu = __shfl(myidx, i);
        const int it = __shfl(myidx, BAG + i);
        const float4 vu = emb4[(size_t)iu * (HIDDEN / 4) + lane];
        const float4 vt = emb4[(size_t)it * (HIDDEN / 4) + lane];
        accU.x += vu.x; accU.y += vu.y; accU.z += vu.z; accU.w += vu.w;
        accT.x += vt.x; accT.y += vt.y; accT.z += vt.z; accT.w += vt.w;
    }
    {
        float4* xv = reinterpret_cast<float4*>(&x_lds[wave][0]);
        xv[lane]      = accU;
        xv[64 + lane] = accT;
    }
    __syncthreads();
    {
        const int r    = tid >> 6;
        const int sub  = tid & 63;
        const int j    = sub >> 1;
        const int half = sub & 1;
        const float4* xr = reinterpret_cast<const float4*>(&x_lds[r][0]) + half * 64;
        const float4* wr = reinterpret_cast<const float4*>(w1 + (size_t)j * (2 * HIDDEN)) + half * 64;
        float s = 0.f;
#pragma unroll 8
        for (int k = 0; k < 64; ++k) {
            const float4 xk = xr[k];
            const float4 wk = wr[k];
            s += xk.x * wk.x + xk.y * wk.y + xk.z * wk.z + xk.w * wk.w;
        }
        s += __shfl_xor(s, 1);
        if (half == 0) { s += b1[j]; y1_lds[r][j] = fminf(fmaxf(s, 0.f), 1.f); }
    }
    __syncthreads();
    if (tid < 4 * 32) {
        const int r = tid >> 5;
        const int j = tid & 31;
        const float* wr = w2 + j * 32;
        float s = b2[j];
#pragma unroll
        for (int k = 0; k < 32; ++k) s += y1_lds[r][k] * wr[k];
        y2_lds[r][j] = fminf(fmaxf(s, 0.f), 1.f);
    }
    __syncthreads();
    if (tid < 4) {
        const int r = tid;
        float s = b3[0];
#pragma unroll
        for (int k = 0; k < 32; ++k) s += y2_lds[r][k] * w3[k];
        out[blockIdx.x * 4 + r] = tanhf(s);
    }
}

extern "C" void kernel_launch(void* const* d_in, const int* in_sizes, int n_in,
                              void* d_out, int out_size, void* d_ws, size_t ws_size,
                              hipStream_t stream) {
    const int*   us   = (const int*)  d_in[0];
    const int*   them = (const int*)  d_in[1];
    const float* emb  = (const float*)d_in[2];
    const float* w1   = (const float*)d_in[3];
    const float* b1   = (const float*)d_in[4];
    const float* w2   = (const float*)d_in[5];
    const float* b2   = (const float*)d_in[6];
    const float* w3   = (const float*)d_in[7];
    const float* b3   = (const float*)d_in[8];
    float* out = (float*)d_out;

    const int batch = in_sizes[0] / BAG;                    // 8192
    const size_t p_bytes = (size_t)FEAT * NJ * sizeof(float);  // 10.5 MB

    if (ws_size >= p_bytes) {
        float* P = (float*)d_ws;
        const int grid0 = (FEAT + 63) / 64;                 // 642
        k0_project<<<grid0, 256, 0, stream>>>(emb, w1, P);
        k1_gather_mlp<<<batch / 4, 256, 0, stream>>>(us, them, P,
                                                     b1, w2, b2, w3, b3, out);
    } else {
        nnue_fused<<<(batch + 3) / 4, 256, 0, stream>>>(us, them, emb,
                                                        w1, b1, w2, b2, w3, b3, out);
    }
}